// Round 1
// baseline (4266.233 us; speedup 1.0000x reference)
//
#include <hip/hip_runtime.h>
#include <math.h>

#define CIN 64
#define COFF 27
#define COUT 64

// ---------------- conv3x3 -> 27 channels (offset conv), pad=1 ----------------
// block: 256 threads = 16x16 pixel tile; computes all 27 output channels.
// grid: (W/16, H/16, B)
template<int H, int W>
__global__ __launch_bounds__(256, 2) void conv_off_kernel(
    const float* __restrict__ src,   // B x 64 x H x W
    const float* __restrict__ wgt,   // 27 x 64 x 3 x 3
    const float* __restrict__ bias,  // 27
    float* __restrict__ dst)         // B x 27 x H x W
{
    const int tx = threadIdx.x & 15;
    const int ty = threadIdx.x >> 4;
    const int x0 = blockIdx.x * 16;
    const int y0 = blockIdx.y * 16;
    const int b  = blockIdx.z;

    __shared__ float lds[16][18 * 18];

    float acc[COFF];
#pragma unroll
    for (int o = 0; o < COFF; ++o) acc[o] = bias[o];

    const float* srcb = src + (size_t)b * CIN * H * W;

    for (int c0 = 0; c0 < CIN; c0 += 16) {
        __syncthreads();
        for (int idx = threadIdx.x; idx < 16 * 324; idx += 256) {
            int c  = idx / 324;
            int r  = idx - c * 324;
            int yy = r / 18;
            int xx = r - yy * 18;
            int gy = y0 - 1 + yy;
            int gx = x0 - 1 + xx;
            float v = 0.f;
            if (gy >= 0 && gy < H && gx >= 0 && gx < W)
                v = srcb[((size_t)(c0 + c) * H + gy) * W + gx];
            lds[c][r] = v;
        }
        __syncthreads();
#pragma unroll 1
        for (int c = 0; c < 16; ++c) {
            const float* wc = wgt + (size_t)(c0 + c) * 9;   // + o*576 + t
#pragma unroll
            for (int t = 0; t < 9; ++t) {
                const int ki = t / 3, kj = t % 3;
                float xv = lds[c][(ty + ki) * 18 + (tx + kj)];
#pragma unroll
                for (int o = 0; o < COFF; ++o)
                    acc[o] = fmaf(xv, wc[o * CIN * 9 + t], acc[o]);
            }
        }
    }

    float* dstb = dst + (size_t)b * COFF * H * W;
#pragma unroll
    for (int o = 0; o < COFF; ++o)
        dstb[((size_t)o * H + (y0 + ty)) * W + (x0 + tx)] = acc[o];
}

// ---------------- conv1x1 residual: r = x * rw + rb ----------------
__global__ __launch_bounds__(256, 2) void conv1x1_kernel(
    const float* __restrict__ x,   // B x 64 x 192 x 192
    const float* __restrict__ rw,  // 64 x 64
    const float* __restrict__ rb,  // 64
    float* __restrict__ dst)       // B x 64 x 192 x 192
{
    const int HW = 192 * 192;
    int p  = blockIdx.x * 256 + threadIdx.x;    // over B*HW (exact)
    int b  = p / HW;
    int hw = p - b * HW;
    const float* xb = x + (size_t)b * CIN * HW + hw;

    float acc[COUT];
#pragma unroll
    for (int o = 0; o < COUT; ++o) acc[o] = rb[o];

#pragma unroll 1
    for (int c = 0; c < CIN; ++c) {
        float v = xb[(size_t)c * HW];
#pragma unroll
        for (int o = 0; o < COUT; ++o)
            acc[o] = fmaf(v, rw[o * CIN + c], acc[o]);
    }

    float* db = dst + (size_t)b * COUT * HW + hw;
#pragma unroll
    for (int o = 0; o < COUT; ++o)
        db[(size_t)o * HW] = acc[o];
}

// ---------------- deformable conv v2 (+ elu, optional +upsampled residual) ----------------
// one thread per output pixel, computes all 64 output channels.
template<int H, int W, bool ADD_RES>
__global__ __launch_bounds__(256, 2) void dcn_kernel(
    const float* __restrict__ src,   // B x 64 x H x W
    const float* __restrict__ off,   // B x 27 x H x W
    const float* __restrict__ wgt,   // 64 x 64 x 3 x 3  -> (o,c,k)
    const float* __restrict__ bias,  // 64
    const float* __restrict__ res,   // B x 64 x H/2 x W/2 (if ADD_RES)
    float* __restrict__ dst)         // B x 64 x H x W
{
    const int HW = H * W;
    int p  = blockIdx.x * 256 + threadIdx.x;    // over B*HW (exact)
    int b  = p / HW;
    int hw = p - b * HW;
    int h  = hw / W;
    int w  = hw - h * W;

    float acc[COUT];
#pragma unroll
    for (int o = 0; o < COUT; ++o) acc[o] = bias[o];

    const float* offp = off + (size_t)b * COFF * HW + hw;
    const float* srcb = src + (size_t)b * CIN * HW;

#pragma unroll 1
    for (int k = 0; k < 9; ++k) {
        float dy = offp[(size_t)(2 * k) * HW];
        float dx = offp[(size_t)(2 * k + 1) * HW];
        float mv = offp[(size_t)(18 + k) * HW];
        float m  = 1.f / (1.f + expf(-mv));

        float yf = (float)(h - 1 + k / 3) + dy;
        float xf = (float)(w - 1 + k % 3) + dx;
        float y0f = floorf(yf), x0f = floorf(xf);
        float wy = yf - y0f, wx = xf - x0f;
        int y0 = (int)y0f, x0 = (int)x0f;
        int y1 = y0 + 1,  x1 = x0 + 1;

        float vy0 = (y0 >= 0 && y0 < H) ? 1.f : 0.f;
        float vy1 = (y1 >= 0 && y1 < H) ? 1.f : 0.f;
        float vx0 = (x0 >= 0 && x0 < W) ? 1.f : 0.f;
        float vx1 = (x1 >= 0 && x1 < W) ? 1.f : 0.f;

        float w00 = (1.f - wy) * (1.f - wx) * vy0 * vx0 * m;
        float w01 = (1.f - wy) * wx         * vy0 * vx1 * m;
        float w10 = wy * (1.f - wx)         * vy1 * vx0 * m;
        float w11 = wy * wx                 * vy1 * vx1 * m;

        int y0c = min(max(y0, 0), H - 1), y1c = min(max(y1, 0), H - 1);
        int x0c = min(max(x0, 0), W - 1), x1c = min(max(x1, 0), W - 1);

        const float* p00 = srcb + (size_t)y0c * W + x0c;
        const float* p01 = srcb + (size_t)y0c * W + x1c;
        const float* p10 = srcb + (size_t)y1c * W + x0c;
        const float* p11 = srcb + (size_t)y1c * W + x1c;
        const float* wk  = wgt + k;                        // + (o*64+c)*9

#pragma unroll 2
        for (int c = 0; c < CIN; ++c) {
            float s = w00 * p00[(size_t)c * HW] + w01 * p01[(size_t)c * HW]
                    + w10 * p10[(size_t)c * HW] + w11 * p11[(size_t)c * HW];
#pragma unroll
            for (int o = 0; o < COUT; ++o)
                acc[o] = fmaf(s, wk[(o * CIN + c) * 9], acc[o]);
        }
    }

    float* dstb = dst + (size_t)b * COUT * HW + hw;

    if (ADD_RES) {
        const int Hh = H / 2, Wh = W / 2;
        int iy = h >> 1, ix = w >> 1;
        int oy = (h & 1) ? min(iy + 1, Hh - 1) : max(iy - 1, 0);
        int ox = (w & 1) ? min(ix + 1, Wh - 1) : max(ix - 1, 0);
        const float* rbase = res + (size_t)b * COUT * Hh * Wh;
#pragma unroll 1
        for (int o = 0; o < COUT; ++o) {
            float v = acc[o];
            v = v > 0.f ? v : (expf(v) - 1.f);
            const float* rp = rbase + (size_t)o * Hh * Wh;
            float r00 = rp[iy * Wh + ix], r01 = rp[iy * Wh + ox];
            float r10 = rp[oy * Wh + ix], r11 = rp[oy * Wh + ox];
            float rv = 0.5625f * r00 + 0.1875f * r01 + 0.1875f * r10 + 0.0625f * r11;
            dstb[(size_t)o * HW] = v + rv;
        }
    } else {
#pragma unroll 1
        for (int o = 0; o < COUT; ++o) {
            float v = acc[o];
            dstb[(size_t)o * HW] = v > 0.f ? v : (expf(v) - 1.f);
        }
    }
}

// ---------------- bilinear 2x upsample (half-pixel, clamped) ----------------
template<int Hh, int Wh>
__global__ __launch_bounds__(256, 4) void upsample_kernel(
    const float* __restrict__ src,  // B x 64 x Hh x Wh
    float* __restrict__ dst)        // B x 64 x 2Hh x 2Wh
{
    const int H = 2 * Hh, W = 2 * Wh;
    int hw = blockIdx.x * 256 + threadIdx.x;   // over H*W (exact)
    int h = hw / W, w = hw - h * W;
    int c = blockIdx.y, b = blockIdx.z;

    int iy = h >> 1, ix = w >> 1;
    int oy = (h & 1) ? min(iy + 1, Hh - 1) : max(iy - 1, 0);
    int ox = (w & 1) ? min(ix + 1, Wh - 1) : max(ix - 1, 0);

    const float* sp = src + (size_t)(b * COUT + c) * Hh * Wh;
    float r00 = sp[iy * Wh + ix], r01 = sp[iy * Wh + ox];
    float r10 = sp[oy * Wh + ix], r11 = sp[oy * Wh + ox];

    dst[((size_t)(b * COUT + c) * H + h) * W + w] =
        0.5625f * r00 + 0.1875f * r01 + 0.1875f * r10 + 0.0625f * r11;
}

extern "C" void kernel_launch(void* const* d_in, const int* in_sizes, int n_in,
                              void* d_out, int out_size, void* d_ws, size_t ws_size,
                              hipStream_t stream) {
    const float* x   = (const float*)d_in[0];
    const float* ow1 = (const float*)d_in[1];
    const float* ob1 = (const float*)d_in[2];
    const float* w1  = (const float*)d_in[3];
    const float* b1  = (const float*)d_in[4];
    const float* ow2 = (const float*)d_in[5];
    const float* ob2 = (const float*)d_in[6];
    const float* w2  = (const float*)d_in[7];
    const float* b2  = (const float*)d_in[8];
    const float* rw  = (const float*)d_in[9];
    const float* rbv = (const float*)d_in[10];
    float* out = (float*)d_out;

    // workspace layout (floats)
    float* ws   = (float*)d_ws;
    float* off1 = ws;                       //  2*27*192*192 = 1,990,656
    float* h1   = off1 + 1990656;           //  2*64*192*192 = 4,718,592
    float* r    = h1   + 4718592;           //  4,718,592
    float* u    = r    + 4718592;           //  2*64*384*384 = 18,874,368
    float* off2 = u    + 18874368;          //  2*27*384*384 = 7,962,624
    // total 38,264,832 floats = 146 MiB

    conv_off_kernel<192, 192><<<dim3(12, 12, 2), 256, 0, stream>>>(x, ow1, ob1, off1);
    conv1x1_kernel<<<288, 256, 0, stream>>>(x, rw, rbv, r);
    dcn_kernel<192, 192, false><<<288, 256, 0, stream>>>(x, off1, w1, b1, nullptr, h1);
    upsample_kernel<192, 192><<<dim3(576, 64, 2), 256, 0, stream>>>(h1, u);
    conv_off_kernel<384, 384><<<dim3(24, 24, 2), 256, 0, stream>>>(u, ow2, ob2, off2);
    dcn_kernel<384, 384, true><<<1152, 256, 0, stream>>>(u, off2, w2, b2, r, out);
}